// Round 2
// 98.032 us; speedup vs baseline: 1.0008x; 1.0008x over previous
//
#include <hip/hip_runtime.h>
#include <math.h>

#define NT 32768
#define SCALEF 4.0f
#define WSIG 0x57AB0000u
#define GSIG 0x6B3C0000u
#define L2E 1.4426950408889634f

typedef _Float16 h2v __attribute__((ext_vector_type(2)));
typedef unsigned uvec4 __attribute__((ext_vector_type(4)));

__device__ __forceinline__ unsigned pk2(float lo, float hi) {
    unsigned a = (unsigned)__builtin_bit_cast(unsigned short, (_Float16)lo);
    unsigned b = (unsigned)__builtin_bit_cast(unsigned short, (_Float16)hi);
    return a | (b << 16);
}
__device__ __forceinline__ float upk_lo(unsigned u) {
    return (float)__builtin_bit_cast(_Float16, (unsigned short)(u & 0xffffu));
}
__device__ __forceinline__ float upk_hi(unsigned u) {
    return (float)__builtin_bit_cast(_Float16, (unsigned short)(u >> 16));
}
__device__ __forceinline__ float dot2(unsigned w, unsigned h, float acc) {
#if defined(__has_builtin) && __has_builtin(__builtin_amdgcn_fdot2)
    return __builtin_amdgcn_fdot2(__builtin_bit_cast(h2v, w),
                                  __builtin_bit_cast(h2v, h), acc, false);
#else
    float r = fmaf(upk_lo(w), upk_lo(h), acc);
    return fmaf(upk_hi(w), upk_hi(h), r);
#endif
}
__device__ __forceinline__ float exp2fast(float x) {
#if defined(__has_builtin) && __has_builtin(__builtin_amdgcn_exp2f)
    return __builtin_amdgcn_exp2f(x);
#else
    return __builtin_exp2f(x);
#endif
}
// tanh(x) = 1 - 2/(1+exp(2x)); exp(2x) = exp2(x * 2*log2e)
__device__ __forceinline__ float tanhfast(float x) {
    return 1.0f - 2.0f * __builtin_amdgcn_rcpf(1.0f + exp2fast(x * (2.0f * L2E)));
}
__device__ __forceinline__ float frame_val(const float* __restrict__ obs,
                                           const float* __restrict__ pred,
                                           int F, int d) {
    return (F < 9) ? obs[F * (NT * 2) + d] : pred[(F - 9) * (NT * 2) + d];
}

// serial-block thread t, slot s owns gate row r (quad-gate layout)
__device__ __forceinline__ int rof2(int k2row) {
    int t = k2row & 255, slot = k2row >> 8;
    int lane = t & 63, wv = t >> 6;
    return (lane & 3) * 128 + wv * 16 + (lane >> 2) + slot * 64;
}

#define QBCAST(dst, src, CTRL)                                                  \
    dst = __int_as_float(__builtin_amdgcn_update_dpp(                           \
        0, __float_as_int(src), (CTRL), 0xF, 0xF, true))

#define PIN16(a0,a1,a2,a3,a4,a5,a6,a7,a8,a9,a10,a11,a12,a13,a14,a15)            \
    asm("" : "+v"(a0), "+v"(a1), "+v"(a2),  "+v"(a3),  "+v"(a4),  "+v"(a5),     \
             "+v"(a6), "+v"(a7), "+v"(a8),  "+v"(a9),  "+v"(a10), "+v"(a11),    \
             "+v"(a12), "+v"(a13), "+v"(a14), "+v"(a15))

// One kernel, 9 blocks x 256. Blocks 0..7: prep. Block 8: serial recurrence.
// Dependency structure is PER-WAVE: serial wave wv's A-weights/gx-slot-A come
// only from prep block wv, B from block 4+wv -> wave-local flag spins.
// v-next: all prep global loads issue at block start (GSIG ~1000cy earlier);
// serial runs step 0 (gx0 computed locally) before any spin; MLP weights are
// L2-warmed at serial start; exp constants folded to raw v_exp (exp2).
__attribute__((amdgpu_waves_per_eu(1, 1)))
__global__ void __launch_bounds__(256) lstm_fused(
    const float* __restrict__ observed, const float* __restrict__ prediction,
    const float* __restrict__ W_emb,    const float* __restrict__ b_emb,
    const float* __restrict__ W_ih,     const float* __restrict__ W_hh,
    const float* __restrict__ b_ih,     const float* __restrict__ b_hh,
    const float* __restrict__ W1, const float* __restrict__ b1,
    const float* __restrict__ W2, const float* __restrict__ b2,
    const float* __restrict__ W3, const float* __restrict__ b3,
    unsigned* __restrict__ wsgx, uvec4* __restrict__ wsw,
    unsigned* __restrict__ flags, float* __restrict__ out)
{
    const int tid = (int)threadIdx.x;   // 0..255

    if (blockIdx.x < 8) {
        // ============================ PREP ============================
        const int b = (int)blockIdx.x;
        __shared__ float    velx[21], vely[21];
        __shared__ unsigned xs_pk[21 * 32];
        __shared__ unsigned wih_pk[64 * 32];   // rotated vs bank conflicts
        __shared__ float    bias64[64];

        // ---- early issue of EVERY global load this block needs ----
        const int row0 = tid >> 3, seg = tid & 7;
        const int row1 = row0 + 32;
        const int rr0 = rof2(b * 64 + row0);
        const int rr1 = rof2(b * 64 + row1);
        // W_hh (gates WSIG -> issued first)
        const float4* s0 = reinterpret_cast<const float4*>(W_hh) + rr0 * 32 + seg * 4;
        const float4* s1 = reinterpret_cast<const float4*>(W_hh) + rr1 * 32 + seg * 4;
        float4 h00 = s0[0], h01 = s0[1], h02 = s0[2], h03 = s0[3];
        float4 h10 = s1[0], h11 = s1[1], h12 = s1[2], h13 = s1[3];
        // W_ih rows
        const float4* i0 = reinterpret_cast<const float4*>(W_ih) + rr0 * 16 + seg * 2;
        const float4* i1 = reinterpret_cast<const float4*>(W_ih) + rr1 * 16 + seg * 2;
        float4 a00 = i0[0], a01 = i0[1];
        float4 a10 = i1[0], a11 = i1[1];
        // embedding weights (fixed e = tid&63 across this thread's xs tasks)
        const int ec = (tid & 63) < 62 ? (tid & 63) : 61;   // clamp: rows 62/63 unused
        float we0 = W_emb[2 * ec], we1 = W_emb[2 * ec + 1], be = b_emb[ec];
        // biases
        float bi = 0.0f, bh = 0.0f;
        if (tid < 64) { int rb = rof2(b * 64 + tid); bi = b_ih[rb]; bh = b_hh[rb]; }
        // velocity frames
        float fax = 0.0f, fay = 0.0f, fbx = 0.0f, fby = 0.0f;
        if (tid < 20) {
            fax = frame_val(observed, prediction, tid,     0);
            fay = frame_val(observed, prediction, tid,     1);
            fbx = frame_val(observed, prediction, tid + 1, 0);
            fby = frame_val(observed, prediction, tid + 1, 1);
        }

        // (1) W_hh -> f16 granule-major workspace (serial block's order)
        {
            int t0 = (b * 64 + row0) & 255, sl0 = (b * 64 + row0) >> 8;
            uvec4 u0, u1;
            u0.x = pk2(h00.x, h00.y); u0.y = pk2(h00.z, h00.w);
            u0.z = pk2(h01.x, h01.y); u0.w = pk2(h01.z, h01.w);
            u1.x = pk2(h02.x, h02.y); u1.y = pk2(h02.z, h02.w);
            u1.z = pk2(h03.x, h03.y); u1.w = pk2(h03.z, h03.w);
            wsw[(sl0 * 16 + seg * 2 + 0) * 256 + t0] = u0;
            wsw[(sl0 * 16 + seg * 2 + 1) * 256 + t0] = u1;
            int t1 = (b * 64 + row1) & 255, sl1 = (b * 64 + row1) >> 8;
            uvec4 u2, u3;
            u2.x = pk2(h10.x, h10.y); u2.y = pk2(h10.z, h10.w);
            u2.z = pk2(h11.x, h11.y); u2.w = pk2(h11.z, h11.w);
            u3.x = pk2(h12.x, h12.y); u3.y = pk2(h12.z, h12.w);
            u3.z = pk2(h13.x, h13.y); u3.w = pk2(h13.z, h13.w);
            wsw[(sl1 * 16 + seg * 2 + 0) * 256 + t1] = u2;
            wsw[(sl1 * 16 + seg * 2 + 1) * 256 + t1] = u3;
        }
        __syncthreads();
        if (tid == 0) {         // weights ready: release-signal
            __threadfence();
            __hip_atomic_store(&flags[b], WSIG + b, __ATOMIC_RELEASE, __HIP_MEMORY_SCOPE_AGENT);
        }

        // (2) stage W_ih (regs -> LDS, rotated), bias64, velocities: no global loads
        wih_pk[row0 * 32 + (((seg * 4 + 0) + row0) & 31)] = pk2(a00.x, a00.y);
        wih_pk[row0 * 32 + (((seg * 4 + 1) + row0) & 31)] = pk2(a00.z, a00.w);
        wih_pk[row0 * 32 + (((seg * 4 + 2) + row0) & 31)] = pk2(a01.x, a01.y);
        wih_pk[row0 * 32 + (((seg * 4 + 3) + row0) & 31)] = pk2(a01.z, a01.w);
        wih_pk[row1 * 32 + (((seg * 4 + 0) + row1) & 31)] = pk2(a10.x, a10.y);
        wih_pk[row1 * 32 + (((seg * 4 + 1) + row1) & 31)] = pk2(a10.z, a10.w);
        wih_pk[row1 * 32 + (((seg * 4 + 2) + row1) & 31)] = pk2(a11.x, a11.y);
        wih_pk[row1 * 32 + (((seg * 4 + 3) + row1) & 31)] = pk2(a11.z, a11.w);
        if (tid < 64) bias64[tid] = bi + bh;
        if (tid < 20) {
            unsigned ua = __float_as_uint(fax) & 0x7fffffffu;
            unsigned ub = __float_as_uint(fbx) & 0x7fffffffu;
            bool m = !((ua > 0x7f800000u) || (ub > 0x7f800000u));   // NaN-safe
            velx[tid + 1] = m ? (fbx - fax) * SCALEF : 0.0f;
            vely[tid + 1] = m ? (fby - fay) * SCALEF : 0.0f;
        }
        if (tid == 20) { velx[0] = 0.0f; vely[0] = 0.0f; }
        __syncthreads();

        // (3) x vectors, packed f16 (pure compute: W_emb/b_emb already in regs)
        unsigned short* xs16 = (unsigned short*)xs_pk;
        for (int idx = tid; idx < 21 * 64; idx += 256) {
            int s = idx >> 6, e = idx & 63;
            float v;
            if (s == 0)      v = (e == 62) ? 1.0f : 0.0f;
            else if (e < 62) v = fmaxf(velx[s] * we0 + vely[s] * we1 + be, 0.0f);
            else             v = 0.0f;
            xs16[s * 64 + e] = __builtin_bit_cast(unsigned short, (_Float16)v);
        }
        __syncthreads();

        // (4) gx table, f16, PAIRED layout: u32[s*256+t] = (slot0 lo, slot1 hi)
        unsigned short* gx16 = (unsigned short*)wsgx;
        for (int task = tid; task < 21 * 64; task += 256) {
            int s = task >> 6, lr = task & 63;
            int k2row = b * 64 + lr;
            int t = k2row & 255, slot = k2row >> 8;
            float acc;
            if (s == 0) {
                acc = bias64[lr] + upk_lo(wih_pk[lr * 32 + ((31 + lr) & 31)]);  // one-hot @ e=62
            } else {
                float a0 = bias64[lr], a1 = 0.0f;
                #pragma unroll
                for (int q = 0; q < 32; q += 2) {
                    a0 = dot2(wih_pk[lr * 32 + ((q + lr) & 31)],     xs_pk[s * 32 + q],     a0);
                    a1 = dot2(wih_pk[lr * 32 + ((q + 1 + lr) & 31)], xs_pk[s * 32 + q + 1], a1);
                }
                acc = a0 + a1;
            }
            gx16[s * 512 + t * 2 + slot] = __builtin_bit_cast(unsigned short, (_Float16)acc);
        }
        __syncthreads();
        if (tid == 0) {         // gx ready: release-signal
            __threadfence();
            __hip_atomic_store(&flags[8 + b], GSIG + b, __ATOMIC_RELEASE, __HIP_MEMORY_SCOPE_AGENT);
        }
        return;
    }

    // ============================ SERIAL ============================
    const int lane = tid & 63;
    const int wv   = tid >> 6;               // wave 0..3
    const int g    = lane & 3;               // gate: 0=i 1=f 2=g 3=o
    const int uA   = wv * 16 + (lane >> 2);  // unit 0..63
    const int uB   = uA + 64;                // unit 64..127

    __shared__ unsigned gxl[21 * 256];       // paired f16 gx (own-slot access only)
    __shared__ uvec4    hqb[2][16];          // double-buffered f16 h (128 units)
    __shared__ float    hfin[128], mlp1[64], mlp2[32];

    // ---- early loads (issue before any spin) ----
    // gx[0] ingredients: bias + one-hot W_ih column 62 (f32, no prep dependency)
    const int rA = rof2(tid), rB = rof2(256 + tid);
    float g0A = b_ih[rA] + b_hh[rA] + W_ih[rA * 64 + 62];
    float g0B = b_ih[rB] + b_hh[rB] + W_ih[rB * 64 + 62];
    // L2-warm the classifier weights (one load per 128B line; consumed below)
    float pf = W1[tid * 32];                          // 32KB, 256 lines
    if (tid < 64) pf += W2[tid * 32];                 // 8KB, 64 lines
    if (tid == 0) pf += W3[0] + b1[0] + b1[32] + b2[0] + b3[0];

    // step-mask via wave-local ballot: no LDS, no barrier (each wave redundant)
    bool mb = true;
    if (lane >= 1 && lane <= 20) {
        float ax = frame_val(observed, prediction, lane - 1, 0);
        float bx = frame_val(observed, prediction, lane,     0);
        unsigned ua = __float_as_uint(ax) & 0x7fffffffu;
        unsigned ub = __float_as_uint(bx) & 0x7fffffffu;
        mb = !((ua > 0x7f800000u) || (ub > 0x7f800000u));
    }
    unsigned mbits = (unsigned)(__ballot(lane < 21 && mb) & 0x1FFFFFull);

    const float scl = (g == 2) ? (2.0f * L2E) : (-L2E);   // log2e folded in
    float cA = 0.0f, cB = 0.0f, hA = 0.0f, hB = 0.0f;
    int cur = 0;

#define STEP_TAIL(preA, preB)                                                   \
    {                                                                           \
        float eA  = exp2fast(scl * (preA));                                     \
        float rcA = __builtin_amdgcn_rcpf(1.0f + eA);                           \
        float actA = (g == 2) ? fmaf(-2.0f, rcA, 1.0f) : rcA;                   \
        float eB  = exp2fast(scl * (preB));                                     \
        float rcB = __builtin_amdgcn_rcpf(1.0f + eB);                           \
        float actB = (g == 2) ? fmaf(-2.0f, rcB, 1.0f) : rcB;                   \
        float giA, gfA, ggA, goA, giB, gfB, ggB, goB;                           \
        QBCAST(giA, actA, 0x00); QBCAST(gfA, actA, 0x55);                       \
        QBCAST(ggA, actA, 0xAA); QBCAST(goA, actA, 0xFF);                       \
        QBCAST(giB, actB, 0x00); QBCAST(gfB, actB, 0x55);                       \
        QBCAST(ggB, actB, 0xAA); QBCAST(goB, actB, 0xFF);                       \
        cA = fmaf(gfA, cA, giA * ggA);  hA = goA * tanhfast(cA);                \
        cB = fmaf(gfB, cB, giB * ggB);  hB = goB * tanhfast(cB);                \
        if ((lane & 3) == 0) {                                                  \
            unsigned short* hw = (unsigned short*)&hqb[cur ^ 1][0];             \
            hw[uA] = __builtin_bit_cast(unsigned short, (_Float16)hA);          \
            hw[uB] = __builtin_bit_cast(unsigned short, (_Float16)hB);          \
        }                                                                       \
        __syncthreads();                                                        \
        cur ^= 1;                                                               \
    }

    // step 0 (h = 0 -> pre-activation is gx0 alone): runs BEFORE any prep spin
    STEP_TAIL(g0A, g0B);
    asm volatile("" :: "v"(pf));   // retire MLP warm loads here (overlapped)

    // ---- wave-local spin: A-weights come ONLY from prep block wv ----
    #pragma unroll 1
    while (__hip_atomic_load(&flags[wv], __ATOMIC_ACQUIRE,
                             __HIP_MEMORY_SCOPE_AGENT) != WSIG + (unsigned)wv) {}
    uvec4 w0  = wsw[ 0 * 256 + tid], w1  = wsw[ 1 * 256 + tid];
    uvec4 w2  = wsw[ 2 * 256 + tid], w3  = wsw[ 3 * 256 + tid];
    uvec4 w4  = wsw[ 4 * 256 + tid], w5  = wsw[ 5 * 256 + tid];
    uvec4 w6  = wsw[ 6 * 256 + tid], w7  = wsw[ 7 * 256 + tid];
    uvec4 w8  = wsw[ 8 * 256 + tid], w9  = wsw[ 9 * 256 + tid];
    uvec4 w10 = wsw[10 * 256 + tid], w11 = wsw[11 * 256 + tid];
    uvec4 w12 = wsw[12 * 256 + tid], w13 = wsw[13 * 256 + tid];
    uvec4 w14 = wsw[14 * 256 + tid], w15 = wsw[15 * 256 + tid];

    // ---- wave-local spin: B-weights from prep block 4+wv ----
    #pragma unroll 1
    while (__hip_atomic_load(&flags[4 + wv], __ATOMIC_ACQUIRE,
                             __HIP_MEMORY_SCOPE_AGENT) != WSIG + 4u + (unsigned)wv) {}
    uvec4 v0  = wsw[16 * 256 + tid], v1  = wsw[17 * 256 + tid];
    uvec4 v2  = wsw[18 * 256 + tid], v3  = wsw[19 * 256 + tid];
    uvec4 v4  = wsw[20 * 256 + tid], v5  = wsw[21 * 256 + tid];
    uvec4 v6  = wsw[22 * 256 + tid], v7  = wsw[23 * 256 + tid];
    uvec4 v8  = wsw[24 * 256 + tid], v9  = wsw[25 * 256 + tid];
    uvec4 v10 = wsw[26 * 256 + tid], v11 = wsw[27 * 256 + tid];
    uvec4 v12 = wsw[28 * 256 + tid], v13 = wsw[29 * 256 + tid];
    uvec4 v14 = wsw[30 * 256 + tid], v15 = wsw[31 * 256 + tid];

    // ---- wave-local spins for gx (blocks wv and 4+wv), own-slot copy ----
    #pragma unroll 1
    while (__hip_atomic_load(&flags[8 + wv], __ATOMIC_ACQUIRE,
                             __HIP_MEMORY_SCOPE_AGENT) != GSIG + (unsigned)wv) {}
    #pragma unroll 1
    while (__hip_atomic_load(&flags[12 + wv], __ATOMIC_ACQUIRE,
                             __HIP_MEMORY_SCOPE_AGENT) != GSIG + 4u + (unsigned)wv) {}
    #pragma unroll
    for (int i = 1; i < 21; ++i) gxl[i * 256 + tid] = wsgx[i * 256 + tid];

// h broadcast via LDS read (same address -> free broadcast, co-issues w/ VALU)
#define G4B(K, WK, VK)                                                          \
    {                                                                           \
        uvec4 hv = hqb[cur][K];                                                 \
        aA0 = dot2(WK.x, hv.x, aA0); aA1 = dot2(WK.y, hv.y, aA1);               \
        aA0 = dot2(WK.z, hv.z, aA0); aA1 = dot2(WK.w, hv.w, aA1);               \
        aB0 = dot2(VK.x, hv.x, aB0); aB1 = dot2(VK.y, hv.y, aB1);               \
        aB0 = dot2(VK.z, hv.z, aB0); aB1 = dot2(VK.w, hv.w, aB1);               \
    }

    #pragma unroll 1
    for (int s = 1; s < 21; ++s) {
        if (mbits & (1u << s)) {
            PIN16(w0,w1,w2,w3,w4,w5,w6,w7,w8,w9,w10,w11,w12,w13,w14,w15);
            PIN16(v0,v1,v2,v3,v4,v5,v6,v7,v8,v9,v10,v11,v12,v13,v14,v15);
            unsigned gp = gxl[s * 256 + tid];
            float aA0 = 0.0f, aA1 = 0.0f, aB0 = 0.0f, aB1 = 0.0f;
            G4B( 0, w0,  v0)  G4B( 1, w1,  v1)  G4B( 2, w2,  v2)  G4B( 3, w3,  v3)
            G4B( 4, w4,  v4)  G4B( 5, w5,  v5)  G4B( 6, w6,  v6)  G4B( 7, w7,  v7)
            G4B( 8, w8,  v8)  G4B( 9, w9,  v9)  G4B(10, w10, v10) G4B(11, w11, v11)
            G4B(12, w12, v12) G4B(13, w13, v13) G4B(14, w14, v14) G4B(15, w15, v15)
            float preA = (aA0 + aA1) + upk_lo(gp);
            float preB = (aB0 + aB1) + upk_hi(gp);
            STEP_TAIL(preA, preB);
        }
    }

    // classifier MLP on final h (W1/W2/W3 are L2-warm from the start prefetch)
    if ((lane & 3) == 0) { hfin[uA] = hA; hfin[uB] = hB; }
    __syncthreads();
    if (tid < 64) {
        const float4* W1r = reinterpret_cast<const float4*>(W1 + tid * 128);
        float a = b1[tid];
        #pragma unroll
        for (int q = 0; q < 32; ++q) {
            float4 w = W1r[q];
            a = fmaf(w.x, hfin[4*q], a);   a = fmaf(w.y, hfin[4*q+1], a);
            a = fmaf(w.z, hfin[4*q+2], a); a = fmaf(w.w, hfin[4*q+3], a);
        }
        mlp1[tid] = fmaxf(a, 0.0f);
    }
    __syncthreads();
    if (tid < 32) {
        const float4* W2r = reinterpret_cast<const float4*>(W2 + tid * 64);
        float a = b2[tid];
        #pragma unroll
        for (int q = 0; q < 16; ++q) {
            float4 w = W2r[q];
            a = fmaf(w.x, mlp1[4*q], a);   a = fmaf(w.y, mlp1[4*q+1], a);
            a = fmaf(w.z, mlp1[4*q+2], a); a = fmaf(w.w, mlp1[4*q+3], a);
        }
        mlp2[tid] = fmaxf(a, 0.0f);
    }
    __syncthreads();
    if (tid == 0) {
        float a = b3[0];
        #pragma unroll
        for (int k = 0; k < 32; ++k) a += W3[k] * mlp2[k];
        out[0] = fmaxf(a, 0.0f);
    }
}

extern "C" void kernel_launch(void* const* d_in, const int* in_sizes, int n_in,
                              void* d_out, int out_size, void* d_ws, size_t ws_size,
                              hipStream_t stream) {
    unsigned* wsgx  = (unsigned*)d_ws;                          // 21504 B (u16[21*512] paired)
    uvec4*    wsw   = (uvec4*)((char*)d_ws + 32768);            // 131072 B
    unsigned* flags = (unsigned*)((char*)d_ws + 196608);        // 16 signature words
    lstm_fused<<<dim3(9), dim3(256), 0, stream>>>(
        (const float*)d_in[0],  (const float*)d_in[1],
        (const float*)d_in[2],  (const float*)d_in[3],
        (const float*)d_in[4],  (const float*)d_in[5],
        (const float*)d_in[6],  (const float*)d_in[7],
        (const float*)d_in[8],  (const float*)d_in[9],
        (const float*)d_in[10], (const float*)d_in[11],
        (const float*)d_in[12], (const float*)d_in[13],
        wsgx, wsw, flags, (float*)d_out);
}